// Round 5
// baseline (656.857 us; speedup 1.0000x reference)
//
#include <hip/hip_runtime.h>
#include <hip/hip_bf16.h>
#include <math.h>

// B x B fp32 sim matrix, B = 8192.
// out[0..B) = uncertainty, out[B..2B) = normalized_entropy
constexpr int BB = 8192;
constexpr float INV_MAX_ENT = 1.0f / 9.010913347279288f;  // 1/log(8192+1e-10)

// ---------------------------------------------------------------------------
// Named-register sorted top-10 insert (no arrays -> no scratch, rule #20).
// Strict > keeps lowest-index-first among equal values (top_k stable order,
// given candidates are presented in increasing index order).
// ---------------------------------------------------------------------------
#define CAS_STEP(tvk, tik)                                  \
  if (_cv > tvk) {                                          \
    float _fv = tvk; tvk = _cv; _cv = _fv;                  \
    int _fi = tik; tik = _ci; _ci = _fi;                    \
  }

#define INS10(vv, ii)                                       \
  if ((vv) > tv9) {                                         \
    float _cv = (vv);                                       \
    int _ci = (ii);                                         \
    CAS_STEP(tv0, ti0) CAS_STEP(tv1, ti1)                   \
    CAS_STEP(tv2, ti2) CAS_STEP(tv3, ti3)                   \
    CAS_STEP(tv4, ti4) CAS_STEP(tv5, ti5)                   \
    CAS_STEP(tv6, ti6) CAS_STEP(tv7, ti7)                   \
    CAS_STEP(tv8, ti8) CAS_STEP(tv9, ti9)                   \
  }

#define DECL10                                              \
  float tv0 = -INFINITY, tv1 = -INFINITY, tv2 = -INFINITY,  \
        tv3 = -INFINITY, tv4 = -INFINITY, tv5 = -INFINITY,  \
        tv6 = -INFINITY, tv7 = -INFINITY, tv8 = -INFINITY,  \
        tv9 = -INFINITY;                                    \
  int ti0 = -1, ti1 = -1, ti2 = -1, ti3 = -1, ti4 = -1,     \
      ti5 = -1, ti6 = -1, ti7 = -1, ti8 = -1, ti9 = -1;

// winner pops its head: static shift-down (all compile-time names)
#define POP_HEAD                                            \
  tv0 = tv1; ti0 = ti1; tv1 = tv2; ti1 = ti2;               \
  tv2 = tv3; ti2 = ti3; tv3 = tv4; ti3 = ti4;               \
  tv4 = tv5; ti4 = ti5; tv5 = tv6; ti5 = ti6;               \
  tv6 = tv7; ti6 = ti7; tv7 = tv8; ti7 = ti8;               \
  tv8 = tv9; ti8 = ti9; tv9 = -INFINITY; ti9 = -1;

// ---------------------------------------------------------------------------
// Kernel A: ONE WAVE PER ROW, no barriers.
// Per lane: online softmax (m,S,W) over 128 elements (batch-of-4 rescale)
// + sorted top-10 in named regs. Then wave-level merges.
//   S(m) = sum exp(t-m), W(m) = sum (t-m)exp(t-m), t = 50*x.
//   rebase m->m': S *= e^(m-m'); W = (W + (m-m')S) e^(m-m').
//   entropy = log S - W/S.
// row_top layout: row_top[kk*BB + row].
// ---------------------------------------------------------------------------
__global__ __launch_bounds__(256) void rows_kernel(const float* __restrict__ sim,
                                                   float* __restrict__ out,
                                                   int* __restrict__ row_top) {
  const int lane = threadIdx.x & 63;
  const int wid = threadIdx.x >> 6;
  const int row = blockIdx.x * 4 + wid;

  const float4* __restrict__ r4 =
      reinterpret_cast<const float4*>(sim + (size_t)row * BB);

  DECL10;
  float m = -1e30f, S = 0.0f, W = 0.0f;

#pragma unroll 4
  for (int j4 = 0; j4 < 32; ++j4) {
    const int f = lane + (j4 << 6);
    float4 q = r4[f];

    // ---- top-10 (pre-filtered; indices = original columns) ----
    float mx4 = fmaxf(fmaxf(q.x, q.y), fmaxf(q.z, q.w));
    if (mx4 > tv9) {
      const int base = f << 2;
      INS10(q.x, base + 0);
      INS10(q.y, base + 1);
      INS10(q.z, base + 2);
      INS10(q.w, base + 3);
    }

    // ---- online softmax batch of 4 ----
    float t0 = 50.0f * q.x, t1 = 50.0f * q.y, t2 = 50.0f * q.z, t3 = 50.0f * q.w;
    float bm = fmaxf(fmaxf(t0, t1), fmaxf(t2, t3));
    float mn = fmaxf(m, bm);
    float r = __expf(m - mn);              // 0 on first batch (m=-1e30)
    float d0 = t0 - mn, d1 = t1 - mn, d2 = t2 - mn, d3 = t3 - mn;
    float e0 = __expf(d0), e1 = __expf(d1), e2 = __expf(d2), e3 = __expf(d3);
    W = fmaf(m - mn, S, W) * r + (d0 * e0 + d1 * e1 + d2 * e2 + d3 * e3);
    S = fmaf(S, r, (e0 + e1) + (e2 + e3));
    m = mn;
  }

  // ---- wave merge of (m, S, W) ----
#pragma unroll
  for (int off = 32; off; off >>= 1) {
    float m2 = __shfl_xor(m, off);
    float S2 = __shfl_xor(S, off);
    float W2 = __shfl_xor(W, off);
    float mn = fmaxf(m, m2);
    float ra = __expf(m - mn);
    float rb = __expf(m2 - mn);
    W = fmaf(m - mn, S, W) * ra + fmaf(m2 - mn, S2, W2) * rb;
    S = S * ra + S2 * rb;
    m = mn;
  }
  if (lane == 0) {
    out[BB + row] = (__logf(S) - W / S) * INV_MAX_ENT;   // eps term <= 8e-7
  }

  // ---- top-10 tournament merge: 10 pops of the per-lane sorted lists ----
#pragma unroll 1
  for (int kk = 0; kk < 10; ++kk) {
    float v = tv0;
    int i = ti0;
#pragma unroll
    for (int off = 32; off; off >>= 1) {
      float ov = __shfl_xor(v, off);
      int oi = __shfl_xor(i, off);
      if (ov > v || (ov == v && oi < i)) { v = ov; i = oi; }
    }
    if (lane == 0) row_top[kk * BB + row] = i;
    if (ti0 == i) { POP_HEAD }   // column indices unique -> exactly one winner
  }
}

// ---------------------------------------------------------------------------
// Kernel B: partial column top-10 over a chunk of rows.
// grid = (BB/256, nch); thread owns one column, streams CH rows, unroll 8.
// Partial layout: pv[(ch*10 + j)*BB + col]  (coalesced for merge)
// ---------------------------------------------------------------------------
__global__ __launch_bounds__(256) void cols_partial_kernel(const float* __restrict__ sim,
                                                           float* __restrict__ pv,
                                                           int* __restrict__ pi,
                                                           int CH) {
  const int col = blockIdx.x * 256 + threadIdx.x;
  const int r0 = blockIdx.y * CH;

  DECL10;

  const float* __restrict__ p = sim + (size_t)r0 * BB + col;

  for (int rr = 0; rr < CH; rr += 8) {
    float v0 = p[0 * BB];
    float v1 = p[1 * BB];
    float v2 = p[2 * BB];
    float v3 = p[3 * BB];
    float v4 = p[4 * BB];
    float v5 = p[5 * BB];
    float v6 = p[6 * BB];
    float v7 = p[7 * BB];
    p += (size_t)8 * BB;
    float mx = fmaxf(fmaxf(fmaxf(v0, v1), fmaxf(v2, v3)),
                     fmaxf(fmaxf(v4, v5), fmaxf(v6, v7)));
    if (mx > tv9) {
      INS10(v0, r0 + rr + 0);
      INS10(v1, r0 + rr + 1);
      INS10(v2, r0 + rr + 2);
      INS10(v3, r0 + rr + 3);
      INS10(v4, r0 + rr + 4);
      INS10(v5, r0 + rr + 5);
      INS10(v6, r0 + rr + 6);
      INS10(v7, r0 + rr + 7);
    }
  }

  float* __restrict__ pvb = pv + (size_t)blockIdx.y * 10 * BB + col;
  int* __restrict__ pib = pi + (size_t)blockIdx.y * 10 * BB + col;
  pvb[0 * BB] = tv0;  pib[0 * BB] = ti0;
  pvb[1 * BB] = tv1;  pib[1 * BB] = ti1;
  pvb[2 * BB] = tv2;  pib[2 * BB] = ti2;
  pvb[3 * BB] = tv3;  pib[3 * BB] = ti3;
  pvb[4 * BB] = tv4;  pib[4 * BB] = ti4;
  pvb[5 * BB] = tv5;  pib[5 * BB] = ti5;
  pvb[6 * BB] = tv6;  pib[6 * BB] = ti6;
  pvb[7 * BB] = tv7;  pib[7 * BB] = ti7;
  pvb[8 * BB] = tv8;  pib[8 * BB] = ti8;
  pvb[9 * BB] = tv9;  pib[9 * BB] = ti9;
}

// ---------------------------------------------------------------------------
// Kernel C: merge partial column top-10 lists (sorted desc, early-break),
// count overlap with row top-10, write uncertainty. One thread per column.
// ---------------------------------------------------------------------------
__global__ __launch_bounds__(256) void merge_kernel(const float* __restrict__ pv,
                                                    const int* __restrict__ pi,
                                                    const int* __restrict__ row_top,
                                                    float* __restrict__ out,
                                                    int nch) {
  const int c = blockIdx.x * 256 + threadIdx.x;

  DECL10;

  for (int ch = 0; ch < nch; ++ch) {
    const float* __restrict__ pvb = pv + (size_t)ch * 10 * BB + c;
    const int* __restrict__ pib = pi + (size_t)ch * 10 * BB + c;
#pragma unroll
    for (int j = 0; j < 10; ++j) {
      float vj = pvb[j * BB];
      if (!(vj > tv9)) break;   // sorted desc: rest of this chunk can't qualify
      int idj = pib[j * BB];
      INS10(vj, idj);
    }
  }

  int cnt = 0;
#pragma unroll
  for (int kk = 0; kk < 10; ++kk) {
    int rt = row_top[kk * BB + c];
    cnt += (rt == ti0) + (rt == ti1) + (rt == ti2) + (rt == ti3) + (rt == ti4) +
           (rt == ti5) + (rt == ti6) + (rt == ti7) + (rt == ti8) + (rt == ti9);
  }
  float ne = out[BB + c];
  float ra = (float)cnt * 0.1f;
  out[c] = (1.0f - ra) * 0.5f + 0.5f * ne;
}

// ---------------------------------------------------------------------------
extern "C" void kernel_launch(void* const* d_in, const int* in_sizes, int n_in,
                              void* d_out, int out_size, void* d_ws, size_t ws_size,
                              hipStream_t stream) {
  const float* sim = (const float*)d_in[0];
  float* out = (float*)d_out;

  // Workspace: row_top [10*BB int] | pv [nch*10*BB f32] | pi [nch*10*BB int]
  int nch = 64;
  while (nch > 1) {
    size_t need = (size_t)BB * 10 * 4 + (size_t)nch * BB * 10 * 8;
    if (need <= ws_size) break;
    nch >>= 1;
  }
  int* row_top = (int*)d_ws;
  float* pv = (float*)((char*)d_ws + (size_t)BB * 10 * 4);
  int* pi = (int*)((char*)pv + (size_t)nch * BB * 10 * 4);

  rows_kernel<<<BB / 4, 256, 0, stream>>>(sim, out, row_top);
  dim3 gb(BB / 256, nch);
  cols_partial_kernel<<<gb, 256, 0, stream>>>(sim, pv, pi, BB / nch);
  merge_kernel<<<BB / 256, 256, 0, stream>>>(pv, pi, row_top, out, nch);
}

// Round 6
// 545.127 us; speedup vs baseline: 1.2050x; 1.2050x over previous
//
#include <hip/hip_runtime.h>
#include <hip/hip_bf16.h>
#include <math.h>

// B x B fp32 sim matrix, B = 8192.
// out[0..B) = uncertainty, out[B..2B) = normalized_entropy
constexpr int BB = 8192;
constexpr float INV_MAX_ENT = 1.0f / 9.010913347279288f;  // 1/log(8192+1e-10)

// ---------------------------------------------------------------------------
// Named-register sorted top-10 insert (no arrays -> no scratch, rule #20).
// Strict > keeps lowest-index-first among equal values (top_k stable order,
// given candidates are presented in increasing index order).
// ---------------------------------------------------------------------------
#define CAS_STEP(tvk, tik)                                  \
  if (_cv > tvk) {                                          \
    float _fv = tvk; tvk = _cv; _cv = _fv;                  \
    int _fi = tik; tik = _ci; _ci = _fi;                    \
  }

#define INS10(vv, ii)                                       \
  if ((vv) > tv9) {                                         \
    float _cv = (vv);                                       \
    int _ci = (ii);                                         \
    CAS_STEP(tv0, ti0) CAS_STEP(tv1, ti1)                   \
    CAS_STEP(tv2, ti2) CAS_STEP(tv3, ti3)                   \
    CAS_STEP(tv4, ti4) CAS_STEP(tv5, ti5)                   \
    CAS_STEP(tv6, ti6) CAS_STEP(tv7, ti7)                   \
    CAS_STEP(tv8, ti8) CAS_STEP(tv9, ti9)                   \
  }

#define DECL10                                              \
  float tv0 = -INFINITY, tv1 = -INFINITY, tv2 = -INFINITY,  \
        tv3 = -INFINITY, tv4 = -INFINITY, tv5 = -INFINITY,  \
        tv6 = -INFINITY, tv7 = -INFINITY, tv8 = -INFINITY,  \
        tv9 = -INFINITY;                                    \
  int ti0 = -1, ti1 = -1, ti2 = -1, ti3 = -1, ti4 = -1,     \
      ti5 = -1, ti6 = -1, ti7 = -1, ti8 = -1, ti9 = -1;

// winner pops its head: static shift-down (all compile-time names)
#define POP_HEAD                                            \
  tv0 = tv1; ti0 = ti1; tv1 = tv2; ti1 = ti2;               \
  tv2 = tv3; ti2 = ti3; tv3 = tv4; ti3 = ti4;               \
  tv4 = tv5; ti4 = ti5; tv5 = tv6; ti5 = ti6;               \
  tv6 = tv7; ti6 = ti7; tv7 = tv8; ti7 = ti8;               \
  tv8 = tv9; ti8 = ti9; tv9 = -INFINITY; ti9 = -1;

// ---------------------------------------------------------------------------
// Kernel A: ONE WAVE PER ROW, no barriers.
// Per lane: online softmax (m,S,W) over 128 elements (batch-of-4 rescale)
// + sorted top-10 in named regs. Then wave-level merges.
// ---------------------------------------------------------------------------
__global__ __launch_bounds__(256) void rows_kernel(const float* __restrict__ sim,
                                                   float* __restrict__ out,
                                                   int* __restrict__ row_top) {
  const int lane = threadIdx.x & 63;
  const int wid = threadIdx.x >> 6;
  const int row = blockIdx.x * 4 + wid;

  const float4* __restrict__ r4 =
      reinterpret_cast<const float4*>(sim + (size_t)row * BB);

  DECL10;
  float m = -1e30f, S = 0.0f, W = 0.0f;

#pragma unroll 4
  for (int j4 = 0; j4 < 32; ++j4) {
    const int f = lane + (j4 << 6);
    float4 q = r4[f];

    // ---- top-10 (pre-filtered; indices = original columns) ----
    float mx4 = fmaxf(fmaxf(q.x, q.y), fmaxf(q.z, q.w));
    if (mx4 > tv9) {
      const int base = f << 2;
      INS10(q.x, base + 0);
      INS10(q.y, base + 1);
      INS10(q.z, base + 2);
      INS10(q.w, base + 3);
    }

    // ---- online softmax batch of 4 ----
    float t0 = 50.0f * q.x, t1 = 50.0f * q.y, t2 = 50.0f * q.z, t3 = 50.0f * q.w;
    float bm = fmaxf(fmaxf(t0, t1), fmaxf(t2, t3));
    float mn = fmaxf(m, bm);
    float r = __expf(m - mn);              // 0 on first batch (m=-1e30)
    float d0 = t0 - mn, d1 = t1 - mn, d2 = t2 - mn, d3 = t3 - mn;
    float e0 = __expf(d0), e1 = __expf(d1), e2 = __expf(d2), e3 = __expf(d3);
    W = fmaf(m - mn, S, W) * r + (d0 * e0 + d1 * e1 + d2 * e2 + d3 * e3);
    S = fmaf(S, r, (e0 + e1) + (e2 + e3));
    m = mn;
  }

  // ---- wave merge of (m, S, W) ----
#pragma unroll
  for (int off = 32; off; off >>= 1) {
    float m2 = __shfl_xor(m, off);
    float S2 = __shfl_xor(S, off);
    float W2 = __shfl_xor(W, off);
    float mn = fmaxf(m, m2);
    float ra = __expf(m - mn);
    float rb = __expf(m2 - mn);
    W = fmaf(m - mn, S, W) * ra + fmaf(m2 - mn, S2, W2) * rb;
    S = S * ra + S2 * rb;
    m = mn;
  }
  if (lane == 0) {
    out[BB + row] = (__logf(S) - W / S) * INV_MAX_ENT;   // eps term <= 8e-7
  }

  // ---- top-10 tournament merge: 10 pops of the per-lane sorted lists ----
#pragma unroll 1
  for (int kk = 0; kk < 10; ++kk) {
    float v = tv0;
    int i = ti0;
#pragma unroll
    for (int off = 32; off; off >>= 1) {
      float ov = __shfl_xor(v, off);
      int oi = __shfl_xor(i, off);
      if (ov > v || (ov == v && oi < i)) { v = ov; i = oi; }
    }
    if (lane == 0) row_top[kk * BB + row] = i;
    if (ti0 == i) { POP_HEAD }   // column indices unique -> exactly one winner
  }
}

// ---------------------------------------------------------------------------
// Kernel B: partial column top-10 over a chunk of rows.
// grid = (BB/256, nch); thread owns one column, streams CH rows, unroll 8.
// Partial layout: pv[(ch*10 + j)*BB + col]
// ---------------------------------------------------------------------------
__global__ __launch_bounds__(256) void cols_partial_kernel(const float* __restrict__ sim,
                                                           float* __restrict__ pv,
                                                           int* __restrict__ pi,
                                                           int CH) {
  const int col = blockIdx.x * 256 + threadIdx.x;
  const int r0 = blockIdx.y * CH;

  DECL10;

  const float* __restrict__ p = sim + (size_t)r0 * BB + col;

  for (int rr = 0; rr < CH; rr += 8) {
    float v0 = p[0 * BB];
    float v1 = p[1 * BB];
    float v2 = p[2 * BB];
    float v3 = p[3 * BB];
    float v4 = p[4 * BB];
    float v5 = p[5 * BB];
    float v6 = p[6 * BB];
    float v7 = p[7 * BB];
    p += (size_t)8 * BB;
    float mx = fmaxf(fmaxf(fmaxf(v0, v1), fmaxf(v2, v3)),
                     fmaxf(fmaxf(v4, v5), fmaxf(v6, v7)));
    if (mx > tv9) {
      INS10(v0, r0 + rr + 0);
      INS10(v1, r0 + rr + 1);
      INS10(v2, r0 + rr + 2);
      INS10(v3, r0 + rr + 3);
      INS10(v4, r0 + rr + 4);
      INS10(v5, r0 + rr + 5);
      INS10(v6, r0 + rr + 6);
      INS10(v7, r0 + rr + 7);
    }
  }

  float* __restrict__ pvb = pv + (size_t)blockIdx.y * 10 * BB + col;
  int* __restrict__ pib = pi + (size_t)blockIdx.y * 10 * BB + col;
  pvb[0 * BB] = tv0;  pib[0 * BB] = ti0;
  pvb[1 * BB] = tv1;  pib[1 * BB] = ti1;
  pvb[2 * BB] = tv2;  pib[2 * BB] = ti2;
  pvb[3 * BB] = tv3;  pib[3 * BB] = ti3;
  pvb[4 * BB] = tv4;  pib[4 * BB] = ti4;
  pvb[5 * BB] = tv5;  pib[5 * BB] = ti5;
  pvb[6 * BB] = tv6;  pib[6 * BB] = ti6;
  pvb[7 * BB] = tv7;  pib[7 * BB] = ti7;
  pvb[8 * BB] = tv8;  pib[8 * BB] = ti8;
  pvb[9 * BB] = tv9;  pib[9 * BB] = ti9;
}

// ---------------------------------------------------------------------------
// Kernel C: ONE WAVE PER COLUMN. Lane l owns partial chunk l (10 independent
// loads, no serial dependence), then a 10-pop shuffle tournament merges the
// 64 sorted lists. Row indices are globally unique across chunks, so the
// popping lane is identified by ti0 == winner. Lanes 0..9 hold row_top
// entries; every pop compares the broadcast winner; sum-reduce the count.
// ---------------------------------------------------------------------------
__global__ __launch_bounds__(256) void merge_kernel(const float* __restrict__ pv,
                                                    const int* __restrict__ pi,
                                                    const int* __restrict__ row_top,
                                                    float* __restrict__ out,
                                                    int nch) {
  const int lane = threadIdx.x & 63;
  const int wid = threadIdx.x >> 6;
  const int c = blockIdx.x * 4 + wid;

  DECL10;

  if (lane < nch) {
    const float* __restrict__ pvb = pv + (size_t)lane * 10 * BB + c;
    const int* __restrict__ pib = pi + (size_t)lane * 10 * BB + c;
    tv0 = pvb[0 * BB];  ti0 = pib[0 * BB];
    tv1 = pvb[1 * BB];  ti1 = pib[1 * BB];
    tv2 = pvb[2 * BB];  ti2 = pib[2 * BB];
    tv3 = pvb[3 * BB];  ti3 = pib[3 * BB];
    tv4 = pvb[4 * BB];  ti4 = pib[4 * BB];
    tv5 = pvb[5 * BB];  ti5 = pib[5 * BB];
    tv6 = pvb[6 * BB];  ti6 = pib[6 * BB];
    tv7 = pvb[7 * BB];  ti7 = pib[7 * BB];
    tv8 = pvb[8 * BB];  ti8 = pib[8 * BB];
    tv9 = pvb[9 * BB];  ti9 = pib[9 * BB];
  }

  // lanes 0..9 hold the row top-10 entry kk=lane for this column
  int rt = -1000000;
  if (lane < 10) rt = row_top[lane * BB + c];

  int cnt = 0;
#pragma unroll 1
  for (int kk = 0; kk < 10; ++kk) {
    float v = tv0;
    int i = ti0;
#pragma unroll
    for (int off = 32; off; off >>= 1) {
      float ov = __shfl_xor(v, off);
      int oi = __shfl_xor(i, off);
      if (ov > v || (ov == v && oi < i)) { v = ov; i = oi; }
    }
    cnt += (rt == i) ? 1 : 0;       // winner broadcast to all lanes
    if (ti0 == i) { POP_HEAD }      // unique row indices -> one popper
  }

#pragma unroll
  for (int off = 32; off; off >>= 1) cnt += __shfl_xor(cnt, off);

  if (lane == 0) {
    float ne = out[BB + c];
    float ra = (float)cnt * 0.1f;
    out[c] = (1.0f - ra) * 0.5f + 0.5f * ne;
  }
}

// ---------------------------------------------------------------------------
extern "C" void kernel_launch(void* const* d_in, const int* in_sizes, int n_in,
                              void* d_out, int out_size, void* d_ws, size_t ws_size,
                              hipStream_t stream) {
  const float* sim = (const float*)d_in[0];
  float* out = (float*)d_out;

  // Workspace: row_top [10*BB int] | pv [nch*10*BB f32] | pi [nch*10*BB int]
  int nch = 64;
  while (nch > 1) {
    size_t need = (size_t)BB * 10 * 4 + (size_t)nch * BB * 10 * 8;
    if (need <= ws_size) break;
    nch >>= 1;
  }
  int* row_top = (int*)d_ws;
  float* pv = (float*)((char*)d_ws + (size_t)BB * 10 * 4);
  int* pi = (int*)((char*)pv + (size_t)nch * BB * 10 * 4);

  rows_kernel<<<BB / 4, 256, 0, stream>>>(sim, out, row_top);
  dim3 gb(BB / 256, nch);
  cols_partial_kernel<<<gb, 256, 0, stream>>>(sim, pv, pi, BB / nch);
  merge_kernel<<<BB / 4, 256, 0, stream>>>(pv, pi, row_top, out, nch);
}